// Round 8
// baseline (1187.439 us; speedup 1.0000x reference)
//
#include <hip/hip_runtime.h>

#define NNODES 100000
#define NGRAPH 256
#define DHID 64
#define DMODEL 192
#define DFF 2048
#define SCAN_CHUNK 512
#define NCH ((NNODES + SCAN_CHUNK - 1) / SCAN_CHUNK)   // 196

__device__ __forceinline__ float bf2f(unsigned short u) {
    union { unsigned int i; float f; } v; v.i = ((unsigned int)u) << 16; return v.f;
}
__device__ __forceinline__ unsigned short f2bf(float f) {
    union { float f; unsigned int i; } v; v.f = f;
    unsigned int r = v.i + 0x7FFF + ((v.i >> 16) & 1);   // round-nearest-even
    return (unsigned short)(r >> 16);
}

// ---------------------------------------------------------------------------
// fp32 -> bf16 bulk convert (for x)
// ---------------------------------------------------------------------------
__global__ __launch_bounds__(256) void f2bf_kernel(
    const float* __restrict__ in, unsigned short* __restrict__ out, int n)
{
    int i = blockIdx.x * blockDim.x + threadIdx.x;
    int n4 = n >> 2;
    for (int t = i; t < n4; t += gridDim.x * blockDim.x) {
        float4 v = ((const float4*)in)[t];
        ushort4 o;
        o.x = f2bf(v.x); o.y = f2bf(v.y); o.z = f2bf(v.z); o.w = f2bf(v.w);
        ((ushort4*)out)[t] = o;
    }
    for (int t = (n4 << 2) + i; t < n; t += gridDim.x * blockDim.x)
        out[t] = f2bf(in[t]);
}

// ---------------------------------------------------------------------------
// CSR construction: histogram -> scan -> counting-sort of edges by dst
// ---------------------------------------------------------------------------
__global__ __launch_bounds__(256) void hist_kernel(
    const int* __restrict__ dstv, int* __restrict__ cnt, int E)
{
    int i = blockIdx.x * blockDim.x + threadIdx.x;
    int stride = gridDim.x * blockDim.x;
    int n4 = E >> 2;
    for (int t = i; t < n4; t += stride) {
        int4 d = ((const int4*)dstv)[t];
        atomicAdd(&cnt[d.x], 1);
        atomicAdd(&cnt[d.y], 1);
        atomicAdd(&cnt[d.z], 1);
        atomicAdd(&cnt[d.w], 1);
    }
    for (int t = (n4 << 2) + i; t < E; t += stride)
        atomicAdd(&cnt[dstv[t]], 1);
}

__global__ __launch_bounds__(SCAN_CHUNK) void scan_chunk_kernel(
    const int* __restrict__ cnt, int* __restrict__ excl,
    int* __restrict__ tot, int n)
{
    __shared__ int buf[SCAN_CHUNK];
    int i = blockIdx.x * SCAN_CHUNK + threadIdx.x;
    int v = (i < n) ? cnt[i] : 0;
    buf[threadIdx.x] = v;
    __syncthreads();
    for (int off = 1; off < SCAN_CHUNK; off <<= 1) {
        int t = (threadIdx.x >= off) ? buf[threadIdx.x - off] : 0;
        __syncthreads();
        buf[threadIdx.x] += t;
        __syncthreads();
    }
    if (i < n) excl[i] = buf[threadIdx.x] - v;
    if (threadIdx.x == SCAN_CHUNK - 1) tot[blockIdx.x] = buf[threadIdx.x];
}

__global__ __launch_bounds__(256) void scan_tot_kernel(int* __restrict__ tot, int nch)
{
    __shared__ int buf[256];
    int v = (threadIdx.x < nch) ? tot[threadIdx.x] : 0;
    buf[threadIdx.x] = v;
    __syncthreads();
    for (int off = 1; off < 256; off <<= 1) {
        int t = (threadIdx.x >= off) ? buf[threadIdx.x - off] : 0;
        __syncthreads();
        buf[threadIdx.x] += t;
        __syncthreads();
    }
    if (threadIdx.x < nch) tot[threadIdx.x] = buf[threadIdx.x] - v;  // exclusive
}

__global__ __launch_bounds__(256) void finalize_rowptr_kernel(
    const int* __restrict__ excl, const int* __restrict__ tot,
    int* __restrict__ rowptr, int* __restrict__ cursor, int n, int E)
{
    for (int i = blockIdx.x * blockDim.x + threadIdx.x; i <= n;
         i += gridDim.x * blockDim.x) {
        if (i < n) {
            int v = excl[i] + tot[i / SCAN_CHUNK];
            rowptr[i] = v;
            cursor[i] = v;
        } else {
            rowptr[n] = E;
        }
    }
}

__global__ __launch_bounds__(256) void sort_edges_kernel(
    const int* __restrict__ srcv, const int* __restrict__ dstv,
    int* __restrict__ cursor, int* __restrict__ out, int E)
{
    int i = blockIdx.x * blockDim.x + threadIdx.x;
    int stride = gridDim.x * blockDim.x;
    int n4 = E >> 2;
    for (int t = i; t < n4; t += stride) {
        int4 s = ((const int4*)srcv)[t];
        int4 d = ((const int4*)dstv)[t];
        out[atomicAdd(&cursor[d.x], 1)] = s.x;
        out[atomicAdd(&cursor[d.y], 1)] = s.y;
        out[atomicAdd(&cursor[d.z], 1)] = s.z;
        out[atomicAdd(&cursor[d.w], 1)] = s.w;
    }
    for (int t = (n4 << 2) + i; t < E; t += stride)
        out[atomicAdd(&cursor[dstv[t]], 1)] = srcv[t];
}

// ---------------------------------------------------------------------------
// Head weight transposes (k-major) so per-output reads coalesce across lanes.
// ---------------------------------------------------------------------------
__global__ __launch_bounds__(256) void transpose_w_kernel(
    const float* __restrict__ qkv_w, const float* __restrict__ aow,
    const float* __restrict__ l1w,  const float* __restrict__ ff1w,
    const float* __restrict__ ff2w,
    float* __restrict__ vwT, float* __restrict__ aowT, float* __restrict__ l1T,
    float* __restrict__ f1T, float* __restrict__ f2T)
{
    const int S1 = DMODEL * DMODEL;          // 36864
    const int S2 = DMODEL * DFF;             // 393216
    int total = 3 * S1 + 2 * S2;
    for (int idx = blockIdx.x * blockDim.x + threadIdx.x; idx < total;
         idx += gridDim.x * blockDim.x) {
        if (idx < 3 * S1) {
            int a = idx / S1, r = idx % S1;
            int k = r / DMODEL, o = r % DMODEL;
            if (a == 0)      vwT[r]  = qkv_w[(2 * DMODEL + o) * DMODEL + k];
            else if (a == 1) aowT[r] = aow[o * DMODEL + k];
            else             l1T[r]  = l1w[o * DMODEL + k];
        } else {
            int r = idx - 3 * S1;
            if (r < S2) {                    // f1T[k*2048+o] = ff1w[o*192+k]
                int k = r >> 11, o = r & (DFF - 1);
                f1T[r] = ff1w[o * DMODEL + k];
            } else {                         // f2T[k*192+o] = ff2w[o*2048+k]
                r -= S2;
                int k = r / DMODEL, o = r % DMODEL;
                f2T[r] = ff2w[o * DFF + k];
            }
        }
    }
}

// ---------------------------------------------------------------------------
// Fused GIN layer.  512-thread blocks (8 waves) amortize the LDS weight copy
// -> 4 blocks/CU, 32 waves/CU at VGPR<=64.  Wave-independent single-node
// loop; bf16 gather; fp32 MLP with lane-major float4 weights in LDS
// (conflict-free ds_read_b128).  Weight staging is COALESCED: thread t loads
// the consecutive float4 w1[4t..4t+3] == w1q[t&15][t>>4].
// ---------------------------------------------------------------------------
__global__ __launch_bounds__(512, 8) void gin_fused_kernel(
    const unsigned short* __restrict__ hin,
    const int* __restrict__ rowptr, const int* __restrict__ srcs,
    const float* __restrict__ w1, const float* __restrict__ b1,
    const float* __restrict__ bng, const float* __restrict__ bnb,
    const float* __restrict__ bnm, const float* __restrict__ bnv,
    const float* __restrict__ w2, const float* __restrict__ b2,
    unsigned short* __restrict__ hout, float* __restrict__ pool,
    const int* __restrict__ batch)
{
    __shared__ float4 w1q[16][64];           // w1q[kc][o] = w1[o][4kc..4kc+3]
    __shared__ float4 w2q[16][64];
    __shared__ float  tbuf[8][68];           // per-wave row, 272B stride

    int tid = threadIdx.x;
    // coalesced staging: 1024 float4s per matrix over 512 threads (2 iters)
    for (int t = tid; t < 1024; t += 512) {
        w1q[t & 15][t >> 4] = *(const float4*)&w1[t * 4];
        w2q[t & 15][t >> 4] = *(const float4*)&w2[t * 4];
    }
    __syncthreads();

    int lane = tid & 63;
    int w    = tid >> 6;

    float rs  = rsqrtf(bnv[lane] + 1e-5f);
    float sc  = bng[lane] * rs;
    float sh  = bnb[lane] - bnm[lane] * sc;
    float bb1 = b1[lane];
    float bb2 = b2[lane];

    int wid    = blockIdx.x * 8 + w;
    int nwaves = gridDim.x * 8;
    int per    = (NNODES + nwaves - 1) / nwaves;
    int n0     = wid * per;
    int n1     = min(n0 + per, NNODES);
    if (n0 >= n1) return;

    float poolacc = 0.0f;
    int   curg    = batch[n0];

    for (int n = n0; n < n1; ++n) {
        // ---- gather: acc = hin[n] + sum_{e->n} hin[src]   (bf16 loads)
        float acc = bf2f(hin[n * DHID + lane]);
        float accb = 0.0f;
        int jb = rowptr[n], je = rowptr[n + 1];
        int j  = jb;
        for (; j + 7 < je; j += 8) {
            int s0 = srcs[j],     s1 = srcs[j + 1], s2 = srcs[j + 2], s3 = srcs[j + 3];
            int s4 = srcs[j + 4], s5 = srcs[j + 5], s6 = srcs[j + 6], s7 = srcs[j + 7];
            float a0 = bf2f(hin[s0 * DHID + lane]);
            float a1 = bf2f(hin[s1 * DHID + lane]);
            float a2 = bf2f(hin[s2 * DHID + lane]);
            float a3 = bf2f(hin[s3 * DHID + lane]);
            float a4 = bf2f(hin[s4 * DHID + lane]);
            float a5 = bf2f(hin[s5 * DHID + lane]);
            float a6 = bf2f(hin[s6 * DHID + lane]);
            float a7 = bf2f(hin[s7 * DHID + lane]);
            acc  += (a0 + a1) + (a2 + a3);
            accb += (a4 + a5) + (a6 + a7);
        }
        for (; j < je; ++j) acc += bf2f(hin[srcs[j] * DHID + lane]);
        acc += accb;

        // ---- matmul1 + BN + relu
        tbuf[w][lane] = acc;                 // wave-private, lockstep-safe
        float y = bb1;
        #pragma unroll
        for (int kc = 0; kc < 16; ++kc) {
            float4 wq = w1q[kc][lane];                       // b128, conflict-free
            float4 t4 = *(const float4*)&tbuf[w][kc * 4];    // b128 broadcast
            y += t4.x * wq.x + t4.y * wq.y + t4.z * wq.z + t4.w * wq.w;
        }
        y = fmaxf(y * sc + sh, 0.0f);

        // ---- matmul2 + relu
        tbuf[w][lane] = y;
        float z = bb2;
        #pragma unroll
        for (int kc = 0; kc < 16; ++kc) {
            float4 wq = w2q[kc][lane];
            float4 t4 = *(const float4*)&tbuf[w][kc * 4];
            z += t4.x * wq.x + t4.y * wq.y + t4.z * wq.z + t4.w * wq.w;
        }
        z = fmaxf(z, 0.0f);

        // ---- store (bf16) + pooled sum (batch sorted -> run accumulation)
        if (hout) hout[n * DHID + lane] = f2bf(z);
        int g = batch[n];
        if (g != curg) {
            atomicAdd(&pool[curg * DHID + lane], poolacc);
            poolacc = 0.0f;
            curg = g;
        }
        poolacc += z;
    }
    atomicAdd(&pool[curg * DHID + lane], poolacc);
}

// ---------------------------------------------------------------------------
// Head A: v = A@vwT, C = A + v@aowT + aob, Bln = LN1(C).  Block per graph.
// ---------------------------------------------------------------------------
__global__ __launch_bounds__(192) void head_a_kernel(
    const float* __restrict__ pools, const float* __restrict__ vwT,
    const float* __restrict__ qkv_b, const float* __restrict__ aowT,
    const float* __restrict__ aob,   const float* __restrict__ ln1g,
    const float* __restrict__ ln1b,  float* __restrict__ Bln)
{
    __shared__ float As[DMODEL], Vs[DMODEL], Cs[DMODEL];
    int g = blockIdx.x, tid = threadIdx.x;

    As[tid] = pools[(tid >> 6) * (NGRAPH * DHID) + g * DHID + (tid & 63)];
    __syncthreads();

    float acc = qkv_b[2 * DMODEL + tid];
    #pragma unroll 8
    for (int k = 0; k < DMODEL; ++k) acc += As[k] * vwT[k * DMODEL + tid];
    Vs[tid] = acc;
    __syncthreads();

    acc = aob[tid];
    #pragma unroll 8
    for (int k = 0; k < DMODEL; ++k) acc += Vs[k] * aowT[k * DMODEL + tid];
    float c = As[tid] + acc;
    Cs[tid] = c;
    __syncthreads();

    float mu = 0.0f;
    #pragma unroll
    for (int k = 0; k < DMODEL; k += 4) {
        float4 q = *(const float4*)&Cs[k];
        mu += (q.x + q.y) + (q.z + q.w);
    }
    mu *= (1.0f / DMODEL);
    float var = 0.0f;
    #pragma unroll
    for (int k = 0; k < DMODEL; k += 4) {
        float4 q = *(const float4*)&Cs[k];
        float d0 = q.x - mu, d1 = q.y - mu, d2 = q.z - mu, d3 = q.w - mu;
        var += (d0 * d0 + d1 * d1) + (d2 * d2 + d3 * d3);
    }
    var *= (1.0f / DMODEL);
    float rstd = rsqrtf(var + 1e-5f);
    Bln[g * DMODEL + tid] = (c - mu) * rstd * ln1g[tid] + ln1b[tid];
}

// ---------------------------------------------------------------------------
// Head B: ffb = relu(Bln @ f1T + b).  Block = 256-output chunk x 8 graphs.
// ---------------------------------------------------------------------------
__global__ __launch_bounds__(256) void head_ff1_kernel(
    const float* __restrict__ Bln, const float* __restrict__ f1T,
    const float* __restrict__ ff1b, float* __restrict__ ffb)
{
    __shared__ float Bs[8][DMODEL];
    int bo = blockIdx.x & 7, bg = blockIdx.x >> 3;
    int tid = threadIdx.x;
    int o = bo * 256 + tid;

    for (int idx = tid; idx < 8 * DMODEL; idx += 256)
        Bs[idx / DMODEL][idx % DMODEL] = Bln[(bg * 8 + idx / DMODEL) * DMODEL + idx % DMODEL];
    __syncthreads();

    float acc[8];
    #pragma unroll
    for (int gi = 0; gi < 8; ++gi) acc[gi] = 0.0f;
    float bias = ff1b[o];

    #pragma unroll 2
    for (int k = 0; k < DMODEL; k += 4) {
        float w0 = f1T[k * DFF + o];
        float w1 = f1T[(k + 1) * DFF + o];
        float w2 = f1T[(k + 2) * DFF + o];
        float w3 = f1T[(k + 3) * DFF + o];
        #pragma unroll
        for (int gi = 0; gi < 8; ++gi) {
            float4 b4 = *(const float4*)&Bs[gi][k];
            acc[gi] += b4.x * w0 + b4.y * w1 + b4.z * w2 + b4.w * w3;
        }
    }
    #pragma unroll
    for (int gi = 0; gi < 8; ++gi)
        ffb[(bg * 8 + gi) * DFF + o] = fmaxf(acc[gi] + bias, 0.0f);
}

// ---------------------------------------------------------------------------
// Head C: ff2 (split-k) + residual + LN2 + lin1 + lin2.  Block = 2 graphs.
// ---------------------------------------------------------------------------
__global__ __launch_bounds__(384) void head_ff2_kernel(
    const float* __restrict__ ffb,  const float* __restrict__ f2T,
    const float* __restrict__ ff2b, const float* __restrict__ Bln,
    const float* __restrict__ ln2g, const float* __restrict__ ln2b,
    const float* __restrict__ l1T,  const float* __restrict__ l1b,
    const float* __restrict__ l2w,  const float* __restrict__ l2b,
    float* __restrict__ out)
{
    __shared__ float ffs[2][DFF];
    __shared__ float ps[2][2][DMODEL];
    __shared__ float Cs[2][DMODEL], As2[2][DMODEL], Bs2[2][DMODEL];

    int g0 = blockIdx.x * 2, tid = threadIdx.x;

    for (int idx = tid; idx < 2 * DFF; idx += 384)
        ffs[idx >> 11][idx & (DFF - 1)] = ffb[g0 * DFF + idx];
    __syncthreads();

    int o  = (tid < DMODEL) ? tid : tid - DMODEL;
    int kh = (tid < DMODEL) ? 0 : 1;
    float acc0 = 0.0f, acc1 = 0.0f;
    int kb = kh * (DFF / 2);
    #pragma unroll 2
    for (int k = kb; k < kb + DFF / 2; k += 4) {
        float w0 = f2T[k * DMODEL + o];
        float w1 = f2T[(k + 1) * DMODEL + o];
        float w2 = f2T[(k + 2) * DMODEL + o];
        float w3 = f2T[(k + 3) * DMODEL + o];
        float4 q0 = *(const float4*)&ffs[0][k];
        float4 q1 = *(const float4*)&ffs[1][k];
        acc0 += q0.x * w0 + q0.y * w1 + q0.z * w2 + q0.w * w3;
        acc1 += q1.x * w0 + q1.y * w1 + q1.z * w2 + q1.w * w3;
    }
    ps[kh][0][o] = acc0;
    ps[kh][1][o] = acc1;
    __syncthreads();

    if (tid < DMODEL) {
        #pragma unroll
        for (int gi = 0; gi < 2; ++gi)
            Cs[gi][tid] = ff2b[tid] + ps[0][gi][tid] + ps[1][gi][tid]
                        + Bln[(g0 + gi) * DMODEL + tid];
    }
    __syncthreads();

    if (tid < DMODEL) {
        #pragma unroll
        for (int gi = 0; gi < 2; ++gi) {
            float mu = 0.0f;
            #pragma unroll
            for (int k = 0; k < DMODEL; k += 4) {
                float4 q = *(const float4*)&Cs[gi][k];
                mu += (q.x + q.y) + (q.z + q.w);
            }
            mu *= (1.0f / DMODEL);
            float var = 0.0f;
            #pragma unroll
            for (int k = 0; k < DMODEL; k += 4) {
                float4 q = *(const float4*)&Cs[gi][k];
                float d0 = q.x - mu, d1 = q.y - mu, d2 = q.z - mu, d3 = q.w - mu;
                var += (d0 * d0 + d1 * d1) + (d2 * d2 + d3 * d3);
            }
            var *= (1.0f / DMODEL);
            float rstd = rsqrtf(var + 1e-5f);
            As2[gi][tid] = (Cs[gi][tid] - mu) * rstd * ln2g[tid] + ln2b[tid];
        }
    }
    __syncthreads();

    if (tid < DMODEL) {
        #pragma unroll
        for (int gi = 0; gi < 2; ++gi) {
            float acc = l1b[tid];
            #pragma unroll 4
            for (int k = 0; k < DMODEL; k += 4) {
                float4 a4 = *(const float4*)&As2[gi][k];
                acc += a4.x * l1T[k * DMODEL + tid] + a4.y * l1T[(k + 1) * DMODEL + tid]
                     + a4.z * l1T[(k + 2) * DMODEL + tid] + a4.w * l1T[(k + 3) * DMODEL + tid];
            }
            Bs2[gi][tid] = fmaxf(acc, 0.0f);
        }
    }
    __syncthreads();

    if (tid < 2) {
        float s = 0.0f;
        #pragma unroll
        for (int k = 0; k < DMODEL; k += 4) {
            float4 b4 = *(const float4*)&Bs2[tid][k];
            float4 w4 = *(const float4*)&l2w[k];
            s += (b4.x * w4.x + b4.y * w4.y) + (b4.z * w4.z + b4.w * w4.w);
        }
        out[g0 + tid] = s + l2b[0];
    }
}

extern "C" void kernel_launch(void* const* d_in, const int* in_sizes, int n_in,
                              void* d_out, int out_size, void* d_ws, size_t ws_size,
                              hipStream_t stream)
{
    const float* x    = (const float*)d_in[0];
    const int*   ei   = (const int*)d_in[1];
    const int*   bat  = (const int*)d_in[2];
    const int    E    = in_sizes[1] / 2;
    const int*   src  = ei;
    const int*   dst  = ei + E;

    const float* nn1[8]; for (int i = 0; i < 8; ++i) nn1[i] = (const float*)d_in[3 + i];
    const float* nn2[8]; for (int i = 0; i < 8; ++i) nn2[i] = (const float*)d_in[11 + i];
    const float* qkv_w = (const float*)d_in[19];
    const float* qkv_b = (const float*)d_in[20];
    const float* aow   = (const float*)d_in[21];
    const float* aob   = (const float*)d_in[22];
    const float* ln1g  = (const float*)d_in[23];
    const float* ln1b  = (const float*)d_in[24];
    const float* ff1w  = (const float*)d_in[25];
    const float* ff1b  = (const float*)d_in[26];
    const float* ff2w  = (const float*)d_in[27];
    const float* ff2b  = (const float*)d_in[28];
    const float* ln2g  = (const float*)d_in[29];
    const float* ln2b  = (const float*)d_in[30];
    const float* l1w   = (const float*)d_in[31];
    const float* l1b   = (const float*)d_in[32];
    const float* l2w   = (const float*)d_in[33];
    const float* l2b   = (const float*)d_in[34];

    const size_t N64 = (size_t)NNODES * DHID;
    const int S1 = DMODEL * DMODEL;     // 36864
    const int S2 = DMODEL * DFF;        // 393216

    // workspace layout: bf16 activations, then floats, then ints
    unsigned short* xb  = (unsigned short*)d_ws;     // N64
    unsigned short* h1b = xb + N64;
    unsigned short* h2b = h1b + N64;
    float* pools = (float*)(h2b + N64);              // 3*G*64
    float* Bln   = pools + 3 * NGRAPH * DHID;        // G*192
    float* ffb   = Bln + NGRAPH * DMODEL;            // G*2048
    float* vwT   = ffb + NGRAPH * DFF;
    float* aowT  = vwT + S1;
    float* l1T   = aowT + S1;
    float* f1T   = l1T + S1;
    float* f2T   = f1T + S2;
    int*   cnt    = (int*)(f2T + S2);
    int*   excl   = cnt + NNODES;
    int*   rowptr = excl + NNODES;                   // N+1
    int*   cursor = rowptr + NNODES + 1;
    int*   tot    = cursor + NNODES;                 // NCH
    int*   srcs   = tot + NCH + 4;                   // E ints

    // ---- CSR build + x->bf16 + weight transposes
    hipMemsetAsync(cnt, 0, NNODES * sizeof(int), stream);
    hipMemsetAsync(pools, 0, 3 * NGRAPH * DHID * sizeof(float), stream);
    f2bf_kernel<<<1024, 256, 0, stream>>>(x, xb, (int)N64);
    hist_kernel<<<1024, 256, 0, stream>>>(dst, cnt, E);
    scan_chunk_kernel<<<NCH, SCAN_CHUNK, 0, stream>>>(cnt, excl, tot, NNODES);
    scan_tot_kernel<<<1, 256, 0, stream>>>(tot, NCH);
    finalize_rowptr_kernel<<<128, 256, 0, stream>>>(excl, tot, rowptr, cursor, NNODES, E);
    sort_edges_kernel<<<1024, 256, 0, stream>>>(src, dst, cursor, srcs, E);
    transpose_w_kernel<<<1024, 256, 0, stream>>>(qkv_w, aow, l1w, ff1w, ff2w,
                                                 vwT, aowT, l1T, f1T, f2T);

    const int LB = 1024;   // 1024 blocks x 8 waves = 8192 waves, ~13 nodes each

    gin_fused_kernel<<<LB, 512, 0, stream>>>(xb, rowptr, srcs,
        nn1[0], nn1[1], nn1[2], nn1[3], nn1[4], nn1[5], nn1[6], nn1[7],
        h1b, pools + 0 * NGRAPH * DHID, bat);

    gin_fused_kernel<<<LB, 512, 0, stream>>>(h1b, rowptr, srcs,
        nn2[0], nn2[1], nn2[2], nn2[3], nn2[4], nn2[5], nn2[6], nn2[7],
        h2b, pools + 1 * NGRAPH * DHID, bat);

    gin_fused_kernel<<<LB, 512, 0, stream>>>(h2b, rowptr, srcs,
        nn2[0], nn2[1], nn2[2], nn2[3], nn2[4], nn2[5], nn2[6], nn2[7],
        nullptr, pools + 2 * NGRAPH * DHID, bat);

    // ---- head
    head_a_kernel<<<NGRAPH, DMODEL, 0, stream>>>(pools, vwT, qkv_b, aowT, aob,
                                                 ln1g, ln1b, Bln);
    head_ff1_kernel<<<256, 256, 0, stream>>>(Bln, f1T, ff1b, ffb);
    head_ff2_kernel<<<NGRAPH / 2, 384, 0, stream>>>(ffb, f2T, ff2b, Bln,
        ln2g, ln2b, l1T, l1b, l2w, l2b, (float*)d_out);
}

// Round 9
// 941.533 us; speedup vs baseline: 1.2612x; 1.2612x over previous
//
#include <hip/hip_runtime.h>

#define NNODES 100000
#define NGRAPH 256
#define DHID 64
#define DMODEL 192
#define DFF 2048
#define SCAN_CHUNK 512
#define NCH ((NNODES + SCAN_CHUNK - 1) / SCAN_CHUNK)   // 196

__device__ __forceinline__ float bf2f(unsigned short u) {
    union { unsigned int i; float f; } v; v.i = ((unsigned int)u) << 16; return v.f;
}
__device__ __forceinline__ unsigned short f2bf(float f) {
    union { float f; unsigned int i; } v; v.f = f;
    unsigned int r = v.i + 0x7FFF + ((v.i >> 16) & 1);   // round-nearest-even
    return (unsigned short)(r >> 16);
}

// ---------------------------------------------------------------------------
// fp32 -> bf16 bulk convert (for x)
// ---------------------------------------------------------------------------
__global__ __launch_bounds__(256) void f2bf_kernel(
    const float* __restrict__ in, unsigned short* __restrict__ out, int n)
{
    int i = blockIdx.x * blockDim.x + threadIdx.x;
    int n4 = n >> 2;
    for (int t = i; t < n4; t += gridDim.x * blockDim.x) {
        float4 v = ((const float4*)in)[t];
        ushort4 o;
        o.x = f2bf(v.x); o.y = f2bf(v.y); o.z = f2bf(v.z); o.w = f2bf(v.w);
        ((ushort4*)out)[t] = o;
    }
    for (int t = (n4 << 2) + i; t < n; t += gridDim.x * blockDim.x)
        out[t] = f2bf(in[t]);
}

// ---------------------------------------------------------------------------
// CSR construction: histogram -> scan -> counting-sort of edges by dst
// ---------------------------------------------------------------------------
__global__ __launch_bounds__(256) void hist_kernel(
    const int* __restrict__ dstv, int* __restrict__ cnt, int E)
{
    int i = blockIdx.x * blockDim.x + threadIdx.x;
    int stride = gridDim.x * blockDim.x;
    int n4 = E >> 2;
    for (int t = i; t < n4; t += stride) {
        int4 d = ((const int4*)dstv)[t];
        atomicAdd(&cnt[d.x], 1);
        atomicAdd(&cnt[d.y], 1);
        atomicAdd(&cnt[d.z], 1);
        atomicAdd(&cnt[d.w], 1);
    }
    for (int t = (n4 << 2) + i; t < E; t += stride)
        atomicAdd(&cnt[dstv[t]], 1);
}

__global__ __launch_bounds__(SCAN_CHUNK) void scan_chunk_kernel(
    const int* __restrict__ cnt, int* __restrict__ excl,
    int* __restrict__ tot, int n)
{
    __shared__ int buf[SCAN_CHUNK];
    int i = blockIdx.x * SCAN_CHUNK + threadIdx.x;
    int v = (i < n) ? cnt[i] : 0;
    buf[threadIdx.x] = v;
    __syncthreads();
    for (int off = 1; off < SCAN_CHUNK; off <<= 1) {
        int t = (threadIdx.x >= off) ? buf[threadIdx.x - off] : 0;
        __syncthreads();
        buf[threadIdx.x] += t;
        __syncthreads();
    }
    if (i < n) excl[i] = buf[threadIdx.x] - v;
    if (threadIdx.x == SCAN_CHUNK - 1) tot[blockIdx.x] = buf[threadIdx.x];
}

__global__ __launch_bounds__(256) void scan_tot_kernel(int* __restrict__ tot, int nch)
{
    __shared__ int buf[256];
    int v = (threadIdx.x < nch) ? tot[threadIdx.x] : 0;
    buf[threadIdx.x] = v;
    __syncthreads();
    for (int off = 1; off < 256; off <<= 1) {
        int t = (threadIdx.x >= off) ? buf[threadIdx.x - off] : 0;
        __syncthreads();
        buf[threadIdx.x] += t;
        __syncthreads();
    }
    if (threadIdx.x < nch) tot[threadIdx.x] = buf[threadIdx.x] - v;  // exclusive
}

__global__ __launch_bounds__(256) void finalize_rowptr_kernel(
    const int* __restrict__ excl, const int* __restrict__ tot,
    int* __restrict__ rowptr, int* __restrict__ cursor, int n, int E)
{
    for (int i = blockIdx.x * blockDim.x + threadIdx.x; i <= n;
         i += gridDim.x * blockDim.x) {
        if (i < n) {
            int v = excl[i] + tot[i / SCAN_CHUNK];
            rowptr[i] = v;
            cursor[i] = v;
        } else {
            rowptr[n] = E;
        }
    }
}

__global__ __launch_bounds__(256) void sort_edges_kernel(
    const int* __restrict__ srcv, const int* __restrict__ dstv,
    int* __restrict__ cursor, int* __restrict__ out, int E)
{
    int i = blockIdx.x * blockDim.x + threadIdx.x;
    int stride = gridDim.x * blockDim.x;
    int n4 = E >> 2;
    for (int t = i; t < n4; t += stride) {
        int4 s = ((const int4*)srcv)[t];
        int4 d = ((const int4*)dstv)[t];
        out[atomicAdd(&cursor[d.x], 1)] = s.x;
        out[atomicAdd(&cursor[d.y], 1)] = s.y;
        out[atomicAdd(&cursor[d.z], 1)] = s.z;
        out[atomicAdd(&cursor[d.w], 1)] = s.w;
    }
    for (int t = (n4 << 2) + i; t < E; t += stride)
        out[atomicAdd(&cursor[dstv[t]], 1)] = srcv[t];
}

// ---------------------------------------------------------------------------
// Head weight transposes (k-major) so per-output reads coalesce across lanes.
// ---------------------------------------------------------------------------
__global__ __launch_bounds__(256) void transpose_w_kernel(
    const float* __restrict__ qkv_w, const float* __restrict__ aow,
    const float* __restrict__ l1w,  const float* __restrict__ ff1w,
    const float* __restrict__ ff2w,
    float* __restrict__ vwT, float* __restrict__ aowT, float* __restrict__ l1T,
    float* __restrict__ f1T, float* __restrict__ f2T)
{
    const int S1 = DMODEL * DMODEL;          // 36864
    const int S2 = DMODEL * DFF;             // 393216
    int total = 3 * S1 + 2 * S2;
    for (int idx = blockIdx.x * blockDim.x + threadIdx.x; idx < total;
         idx += gridDim.x * blockDim.x) {
        if (idx < 3 * S1) {
            int a = idx / S1, r = idx % S1;
            int k = r / DMODEL, o = r % DMODEL;
            if (a == 0)      vwT[r]  = qkv_w[(2 * DMODEL + o) * DMODEL + k];
            else if (a == 1) aowT[r] = aow[o * DMODEL + k];
            else             l1T[r]  = l1w[o * DMODEL + k];
        } else {
            int r = idx - 3 * S1;
            if (r < S2) {                    // f1T[k*2048+o] = ff1w[o*192+k]
                int k = r >> 11, o = r & (DFF - 1);
                f1T[r] = ff1w[o * DMODEL + k];
            } else {                         // f2T[k*192+o] = ff2w[o*2048+k]
                r -= S2;
                int k = r / DMODEL, o = r % DMODEL;
                f2T[r] = ff2w[o * DFF + k];
            }
        }
    }
}

// ---------------------------------------------------------------------------
// Fused GIN layer: R2-proven structure (wave-independent single-node loop,
// fp32 weights in LDS [64][65] = 2-way/free banks), bf16 activations.
// ---------------------------------------------------------------------------
__global__ __launch_bounds__(256) void gin_fused_kernel(
    const unsigned short* __restrict__ hin,
    const int* __restrict__ rowptr, const int* __restrict__ srcs,
    const float* __restrict__ w1, const float* __restrict__ b1,
    const float* __restrict__ bng, const float* __restrict__ bnb,
    const float* __restrict__ bnm, const float* __restrict__ bnv,
    const float* __restrict__ w2, const float* __restrict__ b2,
    unsigned short* __restrict__ hout, float* __restrict__ pool,
    const int* __restrict__ batch)
{
    __shared__ float w1s[DHID][DHID + 1];    // (lane+k)%32 -> 2-way, free
    __shared__ float w2s[DHID][DHID + 1];
    __shared__ float tbuf[4][68];            // per-wave row

    int tid = threadIdx.x;
    for (int idx = tid; idx < DHID * DHID; idx += 256) {
        w1s[idx >> 6][idx & 63] = w1[idx];   // coalesced read, padded write
        w2s[idx >> 6][idx & 63] = w2[idx];
    }
    __syncthreads();

    int lane = tid & 63;
    int w    = tid >> 6;

    float rs  = rsqrtf(bnv[lane] + 1e-5f);
    float sc  = bng[lane] * rs;
    float sh  = bnb[lane] - bnm[lane] * sc;
    float bb1 = b1[lane];
    float bb2 = b2[lane];

    int wid    = blockIdx.x * 4 + w;
    int nwaves = gridDim.x * 4;
    int per    = (NNODES + nwaves - 1) / nwaves;
    int n0     = wid * per;
    int n1     = min(n0 + per, NNODES);
    if (n0 >= n1) return;

    float poolacc = 0.0f;
    int   curg    = batch[n0];

    for (int n = n0; n < n1; ++n) {
        // ---- gather: acc = hin[n] + sum_{e->n} hin[src]   (bf16 loads)
        float acc = bf2f(hin[n * DHID + lane]);
        float accb = 0.0f;
        int jb = rowptr[n], je = rowptr[n + 1];
        int j  = jb;
        for (; j + 7 < je; j += 8) {
            int s0 = srcs[j],     s1 = srcs[j + 1], s2 = srcs[j + 2], s3 = srcs[j + 3];
            int s4 = srcs[j + 4], s5 = srcs[j + 5], s6 = srcs[j + 6], s7 = srcs[j + 7];
            float a0 = bf2f(hin[s0 * DHID + lane]);
            float a1 = bf2f(hin[s1 * DHID + lane]);
            float a2 = bf2f(hin[s2 * DHID + lane]);
            float a3 = bf2f(hin[s3 * DHID + lane]);
            float a4 = bf2f(hin[s4 * DHID + lane]);
            float a5 = bf2f(hin[s5 * DHID + lane]);
            float a6 = bf2f(hin[s6 * DHID + lane]);
            float a7 = bf2f(hin[s7 * DHID + lane]);
            acc  += (a0 + a1) + (a2 + a3);
            accb += (a4 + a5) + (a6 + a7);
        }
        for (; j < je; ++j) acc += bf2f(hin[srcs[j] * DHID + lane]);
        acc += accb;

        // ---- matmul1 + BN + relu  (R2-proven scalar weight reads)
        tbuf[w][lane] = acc;                 // wave-private, lockstep-safe
        float y = bb1;
        #pragma unroll
        for (int k = 0; k < DHID; k += 4) {
            float4 t4 = *(const float4*)&tbuf[w][k];   // b128 broadcast
            y += t4.x * w1s[lane][k]     + t4.y * w1s[lane][k + 1]
               + t4.z * w1s[lane][k + 2] + t4.w * w1s[lane][k + 3];
        }
        y = fmaxf(y * sc + sh, 0.0f);

        // ---- matmul2 + relu
        tbuf[w][lane] = y;
        float z = bb2;
        #pragma unroll
        for (int k = 0; k < DHID; k += 4) {
            float4 t4 = *(const float4*)&tbuf[w][k];
            z += t4.x * w2s[lane][k]     + t4.y * w2s[lane][k + 1]
               + t4.z * w2s[lane][k + 2] + t4.w * w2s[lane][k + 3];
        }
        z = fmaxf(z, 0.0f);

        // ---- store (bf16) + pooled sum (batch sorted -> run accumulation)
        if (hout) hout[n * DHID + lane] = f2bf(z);
        int g = batch[n];
        if (g != curg) {
            atomicAdd(&pool[curg * DHID + lane], poolacc);
            poolacc = 0.0f;
            curg = g;
        }
        poolacc += z;
    }
    atomicAdd(&pool[curg * DHID + lane], poolacc);
}

// ---------------------------------------------------------------------------
// Head A: v = A@vwT, C = A + v@aowT + aob, Bln = LN1(C).  Block per graph.
// ---------------------------------------------------------------------------
__global__ __launch_bounds__(192) void head_a_kernel(
    const float* __restrict__ pools, const float* __restrict__ vwT,
    const float* __restrict__ qkv_b, const float* __restrict__ aowT,
    const float* __restrict__ aob,   const float* __restrict__ ln1g,
    const float* __restrict__ ln1b,  float* __restrict__ Bln)
{
    __shared__ float As[DMODEL], Vs[DMODEL], Cs[DMODEL];
    int g = blockIdx.x, tid = threadIdx.x;

    As[tid] = pools[(tid >> 6) * (NGRAPH * DHID) + g * DHID + (tid & 63)];
    __syncthreads();

    float acc = qkv_b[2 * DMODEL + tid];
    #pragma unroll 8
    for (int k = 0; k < DMODEL; ++k) acc += As[k] * vwT[k * DMODEL + tid];
    Vs[tid] = acc;
    __syncthreads();

    acc = aob[tid];
    #pragma unroll 8
    for (int k = 0; k < DMODEL; ++k) acc += Vs[k] * aowT[k * DMODEL + tid];
    float c = As[tid] + acc;
    Cs[tid] = c;
    __syncthreads();

    float mu = 0.0f;
    #pragma unroll
    for (int k = 0; k < DMODEL; k += 4) {
        float4 q = *(const float4*)&Cs[k];
        mu += (q.x + q.y) + (q.z + q.w);
    }
    mu *= (1.0f / DMODEL);
    float var = 0.0f;
    #pragma unroll
    for (int k = 0; k < DMODEL; k += 4) {
        float4 q = *(const float4*)&Cs[k];
        float d0 = q.x - mu, d1 = q.y - mu, d2 = q.z - mu, d3 = q.w - mu;
        var += (d0 * d0 + d1 * d1) + (d2 * d2 + d3 * d3);
    }
    var *= (1.0f / DMODEL);
    float rstd = rsqrtf(var + 1e-5f);
    Bln[g * DMODEL + tid] = (c - mu) * rstd * ln1g[tid] + ln1b[tid];
}

// ---------------------------------------------------------------------------
// Head B: ffb = relu(Bln @ f1T + b).  Block = 256-output chunk x 8 graphs.
// ---------------------------------------------------------------------------
__global__ __launch_bounds__(256) void head_ff1_kernel(
    const float* __restrict__ Bln, const float* __restrict__ f1T,
    const float* __restrict__ ff1b, float* __restrict__ ffb)
{
    __shared__ float Bs[8][DMODEL];
    int bo = blockIdx.x & 7, bg = blockIdx.x >> 3;
    int tid = threadIdx.x;
    int o = bo * 256 + tid;

    for (int idx = tid; idx < 8 * DMODEL; idx += 256)
        Bs[idx / DMODEL][idx % DMODEL] = Bln[(bg * 8 + idx / DMODEL) * DMODEL + idx % DMODEL];
    __syncthreads();

    float acc[8];
    #pragma unroll
    for (int gi = 0; gi < 8; ++gi) acc[gi] = 0.0f;
    float bias = ff1b[o];

    #pragma unroll 2
    for (int k = 0; k < DMODEL; k += 4) {
        float w0 = f1T[k * DFF + o];
        float w1 = f1T[(k + 1) * DFF + o];
        float w2 = f1T[(k + 2) * DFF + o];
        float w3 = f1T[(k + 3) * DFF + o];
        #pragma unroll
        for (int gi = 0; gi < 8; ++gi) {
            float4 b4 = *(const float4*)&Bs[gi][k];
            acc[gi] += b4.x * w0 + b4.y * w1 + b4.z * w2 + b4.w * w3;
        }
    }
    #pragma unroll
    for (int gi = 0; gi < 8; ++gi)
        ffb[(bg * 8 + gi) * DFF + o] = fmaxf(acc[gi] + bias, 0.0f);
}

// ---------------------------------------------------------------------------
// Head C: ff2 (split-k) + residual + LN2 + lin1 + lin2.  Block = 2 graphs.
// ---------------------------------------------------------------------------
__global__ __launch_bounds__(384) void head_ff2_kernel(
    const float* __restrict__ ffb,  const float* __restrict__ f2T,
    const float* __restrict__ ff2b, const float* __restrict__ Bln,
    const float* __restrict__ ln2g, const float* __restrict__ ln2b,
    const float* __restrict__ l1T,  const float* __restrict__ l1b,
    const float* __restrict__ l2w,  const float* __restrict__ l2b,
    float* __restrict__ out)
{
    __shared__ float ffs[2][DFF];
    __shared__ float ps[2][2][DMODEL];
    __shared__ float Cs[2][DMODEL], As2[2][DMODEL], Bs2[2][DMODEL];

    int g0 = blockIdx.x * 2, tid = threadIdx.x;

    for (int idx = tid; idx < 2 * DFF; idx += 384)
        ffs[idx >> 11][idx & (DFF - 1)] = ffb[g0 * DFF + idx];
    __syncthreads();

    int o  = (tid < DMODEL) ? tid : tid - DMODEL;
    int kh = (tid < DMODEL) ? 0 : 1;
    float acc0 = 0.0f, acc1 = 0.0f;
    int kb = kh * (DFF / 2);
    #pragma unroll 2
    for (int k = kb; k < kb + DFF / 2; k += 4) {
        float w0 = f2T[k * DMODEL + o];
        float w1 = f2T[(k + 1) * DMODEL + o];
        float w2 = f2T[(k + 2) * DMODEL + o];
        float w3 = f2T[(k + 3) * DMODEL + o];
        float4 q0 = *(const float4*)&ffs[0][k];
        float4 q1 = *(const float4*)&ffs[1][k];
        acc0 += q0.x * w0 + q0.y * w1 + q0.z * w2 + q0.w * w3;
        acc1 += q1.x * w0 + q1.y * w1 + q1.z * w2 + q1.w * w3;
    }
    ps[kh][0][o] = acc0;
    ps[kh][1][o] = acc1;
    __syncthreads();

    if (tid < DMODEL) {
        #pragma unroll
        for (int gi = 0; gi < 2; ++gi)
            Cs[gi][tid] = ff2b[tid] + ps[0][gi][tid] + ps[1][gi][tid]
                        + Bln[(g0 + gi) * DMODEL + tid];
    }
    __syncthreads();

    if (tid < DMODEL) {
        #pragma unroll
        for (int gi = 0; gi < 2; ++gi) {
            float mu = 0.0f;
            #pragma unroll
            for (int k = 0; k < DMODEL; k += 4) {
                float4 q = *(const float4*)&Cs[gi][k];
                mu += (q.x + q.y) + (q.z + q.w);
            }
            mu *= (1.0f / DMODEL);
            float var = 0.0f;
            #pragma unroll
            for (int k = 0; k < DMODEL; k += 4) {
                float4 q = *(const float4*)&Cs[gi][k];
                float d0 = q.x - mu, d1 = q.y - mu, d2 = q.z - mu, d3 = q.w - mu;
                var += (d0 * d0 + d1 * d1) + (d2 * d2 + d3 * d3);
            }
            var *= (1.0f / DMODEL);
            float rstd = rsqrtf(var + 1e-5f);
            As2[gi][tid] = (Cs[gi][tid] - mu) * rstd * ln2g[tid] + ln2b[tid];
        }
    }
    __syncthreads();

    if (tid < DMODEL) {
        #pragma unroll
        for (int gi = 0; gi < 2; ++gi) {
            float acc = l1b[tid];
            #pragma unroll 4
            for (int k = 0; k < DMODEL; k += 4) {
                float4 a4 = *(const float4*)&As2[gi][k];
                acc += a4.x * l1T[k * DMODEL + tid] + a4.y * l1T[(k + 1) * DMODEL + tid]
                     + a4.z * l1T[(k + 2) * DMODEL + tid] + a4.w * l1T[(k + 3) * DMODEL + tid];
            }
            Bs2[gi][tid] = fmaxf(acc, 0.0f);
        }
    }
    __syncthreads();

    if (tid < 2) {
        float s = 0.0f;
        #pragma unroll
        for (int k = 0; k < DMODEL; k += 4) {
            float4 b4 = *(const float4*)&Bs2[tid][k];
            float4 w4 = *(const float4*)&l2w[k];
            s += (b4.x * w4.x + b4.y * w4.y) + (b4.z * w4.z + b4.w * w4.w);
        }
        out[g0 + tid] = s + l2b[0];
    }
}

extern "C" void kernel_launch(void* const* d_in, const int* in_sizes, int n_in,
                              void* d_out, int out_size, void* d_ws, size_t ws_size,
                              hipStream_t stream)
{
    const float* x    = (const float*)d_in[0];
    const int*   ei   = (const int*)d_in[1];
    const int*   bat  = (const int*)d_in[2];
    const int    E    = in_sizes[1] / 2;
    const int*   src  = ei;
    const int*   dst  = ei + E;

    const float* nn1[8]; for (int i = 0; i < 8; ++i) nn1[i] = (const float*)d_in[3 + i];
    const float* nn2[8]; for (int i = 0; i < 8; ++i) nn2[i] = (const float*)d_in[11 + i];
    const float* qkv_w = (const float*)d_in[19];
    const float* qkv_b = (const float*)d_in[20];
    const float* aow   = (const float*)d_in[21];
    const float* aob   = (const float*)d_in[22];
    const float* ln1g  = (const float*)d_in[23];
    const float* ln1b  = (const float*)d_in[24];
    const float* ff1w  = (const float*)d_in[25];
    const float* ff1b  = (const float*)d_in[26];
    const float* ff2w  = (const float*)d_in[27];
    const float* ff2b  = (const float*)d_in[28];
    const float* ln2g  = (const float*)d_in[29];
    const float* ln2b  = (const float*)d_in[30];
    const float* l1w   = (const float*)d_in[31];
    const float* l1b   = (const float*)d_in[32];
    const float* l2w   = (const float*)d_in[33];
    const float* l2b   = (const float*)d_in[34];

    const size_t N64 = (size_t)NNODES * DHID;
    const int S1 = DMODEL * DMODEL;     // 36864
    const int S2 = DMODEL * DFF;        // 393216

    // workspace layout: bf16 activations, then floats, then ints
    unsigned short* xb  = (unsigned short*)d_ws;     // N64
    unsigned short* h1b = xb + N64;
    unsigned short* h2b = h1b + N64;
    float* pools = (float*)(h2b + N64);              // 3*G*64
    float* Bln   = pools + 3 * NGRAPH * DHID;        // G*192
    float* ffb   = Bln + NGRAPH * DMODEL;            // G*2048
    float* vwT   = ffb + NGRAPH * DFF;
    float* aowT  = vwT + S1;
    float* l1T   = aowT + S1;
    float* f1T   = l1T + S1;
    float* f2T   = f1T + S2;
    int*   cnt    = (int*)(f2T + S2);
    int*   excl   = cnt + NNODES;
    int*   rowptr = excl + NNODES;                   // N+1
    int*   cursor = rowptr + NNODES + 1;
    int*   tot    = cursor + NNODES;                 // NCH
    int*   srcs   = tot + NCH + 4;                   // E ints

    // ---- CSR build + x->bf16 + weight transposes
    hipMemsetAsync(cnt, 0, NNODES * sizeof(int), stream);
    hipMemsetAsync(pools, 0, 3 * NGRAPH * DHID * sizeof(float), stream);
    f2bf_kernel<<<1024, 256, 0, stream>>>(x, xb, (int)N64);
    hist_kernel<<<1024, 256, 0, stream>>>(dst, cnt, E);
    scan_chunk_kernel<<<NCH, SCAN_CHUNK, 0, stream>>>(cnt, excl, tot, NNODES);
    scan_tot_kernel<<<1, 256, 0, stream>>>(tot, NCH);
    finalize_rowptr_kernel<<<128, 256, 0, stream>>>(excl, tot, rowptr, cursor, NNODES, E);
    sort_edges_kernel<<<1024, 256, 0, stream>>>(src, dst, cursor, srcs, E);
    transpose_w_kernel<<<1024, 256, 0, stream>>>(qkv_w, aow, l1w, ff1w, ff2w,
                                                 vwT, aowT, l1T, f1T, f2T);

    const int LB = 1024;   // 4096 independent waves, ~25 nodes each

    gin_fused_kernel<<<LB, 256, 0, stream>>>(xb, rowptr, srcs,
        nn1[0], nn1[1], nn1[2], nn1[3], nn1[4], nn1[5], nn1[6], nn1[7],
        h1b, pools + 0 * NGRAPH * DHID, bat);

    gin_fused_kernel<<<LB, 256, 0, stream>>>(h1b, rowptr, srcs,
        nn2[0], nn2[1], nn2[2], nn2[3], nn2[4], nn2[5], nn2[6], nn2[7],
        h2b, pools + 1 * NGRAPH * DHID, bat);

    gin_fused_kernel<<<LB, 256, 0, stream>>>(h2b, rowptr, srcs,
        nn2[0], nn2[1], nn2[2], nn2[3], nn2[4], nn2[5], nn2[6], nn2[7],
        nullptr, pools + 2 * NGRAPH * DHID, bat);

    // ---- head
    head_a_kernel<<<NGRAPH, DMODEL, 0, stream>>>(pools, vwT, qkv_b, aowT, aob,
                                                 ln1g, ln1b, Bln);
    head_ff1_kernel<<<256, 256, 0, stream>>>(Bln, f1T, ff1b, ffb);
    head_ff2_kernel<<<NGRAPH / 2, 384, 0, stream>>>(ffb, f2T, ff2b, Bln,
        ln2g, ln2b, l1T, l1b, l2w, l2b, (float*)d_out);
}

// Round 10
// 852.157 us; speedup vs baseline: 1.3935x; 1.1049x over previous
//
#include <hip/hip_runtime.h>

#define NNODES 100000
#define NGRAPH 256
#define DHID 64
#define DMODEL 192
#define DFF 2048
#define SCAN_CHUNK 512
#define NCH ((NNODES + SCAN_CHUNK - 1) / SCAN_CHUNK)   // 196

__device__ __forceinline__ unsigned short f2bf(float f) {
    union { float f; unsigned int i; } v; v.f = f;
    unsigned int r = v.i + 0x7FFF + ((v.i >> 16) & 1);   // round-nearest-even
    return (unsigned short)(r >> 16);
}

// ---------------------------------------------------------------------------
// CSR construction: histogram -> scan -> counting-sort of edges by dst
// ---------------------------------------------------------------------------
__global__ __launch_bounds__(256) void hist_kernel(
    const int* __restrict__ dstv, int* __restrict__ cnt, int E)
{
    int i = blockIdx.x * blockDim.x + threadIdx.x;
    int stride = gridDim.x * blockDim.x;
    int n4 = E >> 2;
    for (int t = i; t < n4; t += stride) {
        int4 d = ((const int4*)dstv)[t];
        atomicAdd(&cnt[d.x], 1);
        atomicAdd(&cnt[d.y], 1);
        atomicAdd(&cnt[d.z], 1);
        atomicAdd(&cnt[d.w], 1);
    }
    for (int t = (n4 << 2) + i; t < E; t += stride)
        atomicAdd(&cnt[dstv[t]], 1);
}

__global__ __launch_bounds__(SCAN_CHUNK) void scan_chunk_kernel(
    const int* __restrict__ cnt, int* __restrict__ excl,
    int* __restrict__ tot, int n)
{
    __shared__ int buf[SCAN_CHUNK];
    int i = blockIdx.x * SCAN_CHUNK + threadIdx.x;
    int v = (i < n) ? cnt[i] : 0;
    buf[threadIdx.x] = v;
    __syncthreads();
    for (int off = 1; off < SCAN_CHUNK; off <<= 1) {
        int t = (threadIdx.x >= off) ? buf[threadIdx.x - off] : 0;
        __syncthreads();
        buf[threadIdx.x] += t;
        __syncthreads();
    }
    if (i < n) excl[i] = buf[threadIdx.x] - v;
    if (threadIdx.x == SCAN_CHUNK - 1) tot[blockIdx.x] = buf[threadIdx.x];
}

__global__ __launch_bounds__(256) void scan_tot_kernel(int* __restrict__ tot, int nch)
{
    __shared__ int buf[256];
    int v = (threadIdx.x < nch) ? tot[threadIdx.x] : 0;
    buf[threadIdx.x] = v;
    __syncthreads();
    for (int off = 1; off < 256; off <<= 1) {
        int t = (threadIdx.x >= off) ? buf[threadIdx.x - off] : 0;
        __syncthreads();
        buf[threadIdx.x] += t;
        __syncthreads();
    }
    if (threadIdx.x < nch) tot[threadIdx.x] = buf[threadIdx.x] - v;  // exclusive
}

__global__ __launch_bounds__(256) void finalize_rowptr_kernel(
    const int* __restrict__ excl, const int* __restrict__ tot,
    int* __restrict__ rowptr, int* __restrict__ cursor, int n, int E)
{
    for (int i = blockIdx.x * blockDim.x + threadIdx.x; i <= n;
         i += gridDim.x * blockDim.x) {
        if (i < n) {
            int v = excl[i] + tot[i / SCAN_CHUNK];
            rowptr[i] = v;
            cursor[i] = v;
        } else {
            rowptr[n] = E;
        }
    }
}

__global__ __launch_bounds__(256) void sort_edges_kernel(
    const int* __restrict__ srcv, const int* __restrict__ dstv,
    int* __restrict__ cursor, int* __restrict__ out, int E)
{
    int i = blockIdx.x * blockDim.x + threadIdx.x;
    int stride = gridDim.x * blockDim.x;
    int n4 = E >> 2;
    for (int t = i; t < n4; t += stride) {
        int4 s = ((const int4*)srcv)[t];
        int4 d = ((const int4*)dstv)[t];
        out[atomicAdd(&cursor[d.x], 1)] = s.x;
        out[atomicAdd(&cursor[d.y], 1)] = s.y;
        out[atomicAdd(&cursor[d.z], 1)] = s.z;
        out[atomicAdd(&cursor[d.w], 1)] = s.w;
    }
    for (int t = (n4 << 2) + i; t < E; t += stride)
        out[atomicAdd(&cursor[dstv[t]], 1)] = srcv[t];
}

// ---------------------------------------------------------------------------
// Head weight transposes (k-major) so per-output reads coalesce across lanes.
// ---------------------------------------------------------------------------
__global__ __launch_bounds__(256) void transpose_w_kernel(
    const float* __restrict__ qkv_w, const float* __restrict__ aow,
    const float* __restrict__ l1w,  const float* __restrict__ ff1w,
    const float* __restrict__ ff2w,
    float* __restrict__ vwT, float* __restrict__ aowT, float* __restrict__ l1T,
    float* __restrict__ f1T, float* __restrict__ f2T)
{
    const int S1 = DMODEL * DMODEL;          // 36864
    const int S2 = DMODEL * DFF;             // 393216
    int total = 3 * S1 + 2 * S2;
    for (int idx = blockIdx.x * blockDim.x + threadIdx.x; idx < total;
         idx += gridDim.x * blockDim.x) {
        if (idx < 3 * S1) {
            int a = idx / S1, r = idx % S1;
            int k = r / DMODEL, o = r % DMODEL;
            if (a == 0)      vwT[r]  = qkv_w[(2 * DMODEL + o) * DMODEL + k];
            else if (a == 1) aowT[r] = aow[o * DMODEL + k];
            else             l1T[r]  = l1w[o * DMODEL + k];
        } else {
            int r = idx - 3 * S1;
            if (r < S2) {                    // f1T[k*2048+o] = ff1w[o*192+k]
                int k = r >> 11, o = r & (DFF - 1);
                f1T[r] = ff1w[o * DMODEL + k];
            } else {                         // f2T[k*192+o] = ff2w[o*2048+k]
                r -= S2;
                int k = r / DMODEL, o = r % DMODEL;
                f2T[r] = ff2w[o * DFF + k];
            }
        }
    }
}

// ---------------------------------------------------------------------------
// Fused GIN layer.  fp32 gather (R2-proven, issue-lean) + fp32 MLP with
// bf16-PACKED weights in LDS: 2x 64x33 uints = 16.9KB total -> ~7 blocks/CU
// (28 waves) instead of 4 (16 waves).  Weight read = ds_read_b32 (2 weights),
// (lane+kc)%32 banks = 2-way = free; unpack = 2 VALU (shift/mask as f32 bits).
// ---------------------------------------------------------------------------
__global__ __launch_bounds__(256) void gin_fused_kernel(
    const float* __restrict__ hin,
    const int* __restrict__ rowptr, const int* __restrict__ srcs,
    const float* __restrict__ w1, const float* __restrict__ b1,
    const float* __restrict__ bng, const float* __restrict__ bnb,
    const float* __restrict__ bnm, const float* __restrict__ bnv,
    const float* __restrict__ w2, const float* __restrict__ b2,
    float* __restrict__ hout, float* __restrict__ pool,
    const int* __restrict__ batch)
{
    __shared__ unsigned int w1p[DHID][33];   // w1p[o][kc] = bf16 pair (k=2kc,2kc+1)
    __shared__ unsigned int w2p[DHID][33];
    __shared__ float tbuf[4][68];            // per-wave row, 272B = 17*16B

    int tid = threadIdx.x;
    for (int idx = tid; idx < DHID * 32; idx += 256) {   // 2048 pairs each
        int o = idx >> 5, kc = idx & 31;
        float2 p1 = *(const float2*)&w1[idx * 2];        // coalesced 8B
        float2 p2 = *(const float2*)&w2[idx * 2];
        w1p[o][kc] = ((unsigned int)f2bf(p1.y) << 16) | f2bf(p1.x);
        w2p[o][kc] = ((unsigned int)f2bf(p2.y) << 16) | f2bf(p2.x);
    }
    __syncthreads();

    int lane = tid & 63;
    int w    = tid >> 6;

    float rs  = rsqrtf(bnv[lane] + 1e-5f);
    float sc  = bng[lane] * rs;
    float sh  = bnb[lane] - bnm[lane] * sc;
    float bb1 = b1[lane];
    float bb2 = b2[lane];

    int wid    = blockIdx.x * 4 + w;
    int nwaves = gridDim.x * 4;
    int per    = (NNODES + nwaves - 1) / nwaves;
    int n0     = wid * per;
    int n1     = min(n0 + per, NNODES);
    if (n0 >= n1) return;

    float poolacc = 0.0f;
    int   curg    = batch[n0];

    for (int n = n0; n < n1; ++n) {
        // ---- gather: acc = hin[n] + sum_{e->n} hin[src]   (fp32 loads)
        float acc = hin[n * DHID + lane];
        float accb = 0.0f;
        int jb = rowptr[n], je = rowptr[n + 1];
        int j  = jb;
        for (; j + 7 < je; j += 8) {
            int s0 = srcs[j],     s1 = srcs[j + 1], s2 = srcs[j + 2], s3 = srcs[j + 3];
            int s4 = srcs[j + 4], s5 = srcs[j + 5], s6 = srcs[j + 6], s7 = srcs[j + 7];
            float a0 = hin[s0 * DHID + lane];
            float a1 = hin[s1 * DHID + lane];
            float a2 = hin[s2 * DHID + lane];
            float a3 = hin[s3 * DHID + lane];
            float a4 = hin[s4 * DHID + lane];
            float a5 = hin[s5 * DHID + lane];
            float a6 = hin[s6 * DHID + lane];
            float a7 = hin[s7 * DHID + lane];
            acc  += (a0 + a1) + (a2 + a3);
            accb += (a4 + a5) + (a6 + a7);
        }
        for (; j < je; ++j) acc += hin[srcs[j] * DHID + lane];
        acc += accb;

        // ---- matmul1 + BN + relu   (bf16-packed weights, fp32 accumulate)
        tbuf[w][lane] = acc;                 // wave-private, lockstep-safe
        float y = bb1;
        #pragma unroll
        for (int q = 0; q < 16; ++q) {
            float4 t4 = *(const float4*)&tbuf[w][q * 4];   // b128 broadcast
            unsigned int pa = w1p[lane][q * 2];
            unsigned int pb = w1p[lane][q * 2 + 1];
            y += t4.x * __uint_as_float(pa << 16)
               + t4.y * __uint_as_float(pa & 0xffff0000u)
               + t4.z * __uint_as_float(pb << 16)
               + t4.w * __uint_as_float(pb & 0xffff0000u);
        }
        y = fmaxf(y * sc + sh, 0.0f);

        // ---- matmul2 + relu
        tbuf[w][lane] = y;
        float z = bb2;
        #pragma unroll
        for (int q = 0; q < 16; ++q) {
            float4 t4 = *(const float4*)&tbuf[w][q * 4];
            unsigned int pa = w2p[lane][q * 2];
            unsigned int pb = w2p[lane][q * 2 + 1];
            z += t4.x * __uint_as_float(pa << 16)
               + t4.y * __uint_as_float(pa & 0xffff0000u)
               + t4.z * __uint_as_float(pb << 16)
               + t4.w * __uint_as_float(pb & 0xffff0000u);
        }
        z = fmaxf(z, 0.0f);

        // ---- store (fp32) + pooled sum (batch sorted -> run accumulation)
        if (hout) hout[n * DHID + lane] = z;
        int g = batch[n];
        if (g != curg) {
            atomicAdd(&pool[curg * DHID + lane], poolacc);
            poolacc = 0.0f;
            curg = g;
        }
        poolacc += z;
    }
    atomicAdd(&pool[curg * DHID + lane], poolacc);
}

// ---------------------------------------------------------------------------
// Head A: v = A@vwT, C = A + v@aowT + aob, Bln = LN1(C).  Block per graph.
// ---------------------------------------------------------------------------
__global__ __launch_bounds__(192) void head_a_kernel(
    const float* __restrict__ pools, const float* __restrict__ vwT,
    const float* __restrict__ qkv_b, const float* __restrict__ aowT,
    const float* __restrict__ aob,   const float* __restrict__ ln1g,
    const float* __restrict__ ln1b,  float* __restrict__ Bln)
{
    __shared__ float As[DMODEL], Vs[DMODEL], Cs[DMODEL];
    int g = blockIdx.x, tid = threadIdx.x;

    As[tid] = pools[(tid >> 6) * (NGRAPH * DHID) + g * DHID + (tid & 63)];
    __syncthreads();

    float acc = qkv_b[2 * DMODEL + tid];
    #pragma unroll 8
    for (int k = 0; k < DMODEL; ++k) acc += As[k] * vwT[k * DMODEL + tid];
    Vs[tid] = acc;
    __syncthreads();

    acc = aob[tid];
    #pragma unroll 8
    for (int k = 0; k < DMODEL; ++k) acc += Vs[k] * aowT[k * DMODEL + tid];
    float c = As[tid] + acc;
    Cs[tid] = c;
    __syncthreads();

    float mu = 0.0f;
    #pragma unroll
    for (int k = 0; k < DMODEL; k += 4) {
        float4 q = *(const float4*)&Cs[k];
        mu += (q.x + q.y) + (q.z + q.w);
    }
    mu *= (1.0f / DMODEL);
    float var = 0.0f;
    #pragma unroll
    for (int k = 0; k < DMODEL; k += 4) {
        float4 q = *(const float4*)&Cs[k];
        float d0 = q.x - mu, d1 = q.y - mu, d2 = q.z - mu, d3 = q.w - mu;
        var += (d0 * d0 + d1 * d1) + (d2 * d2 + d3 * d3);
    }
    var *= (1.0f / DMODEL);
    float rstd = rsqrtf(var + 1e-5f);
    Bln[g * DMODEL + tid] = (c - mu) * rstd * ln1g[tid] + ln1b[tid];
}

// ---------------------------------------------------------------------------
// Head B: ffb = relu(Bln @ f1T + b).  Block = 256-output chunk x 8 graphs.
// ---------------------------------------------------------------------------
__global__ __launch_bounds__(256) void head_ff1_kernel(
    const float* __restrict__ Bln, const float* __restrict__ f1T,
    const float* __restrict__ ff1b, float* __restrict__ ffb)
{
    __shared__ float Bs[8][DMODEL];
    int bo = blockIdx.x & 7, bg = blockIdx.x >> 3;
    int tid = threadIdx.x;
    int o = bo * 256 + tid;

    for (int idx = tid; idx < 8 * DMODEL; idx += 256)
        Bs[idx / DMODEL][idx % DMODEL] = Bln[(bg * 8 + idx / DMODEL) * DMODEL + idx % DMODEL];
    __syncthreads();

    float acc[8];
    #pragma unroll
    for (int gi = 0; gi < 8; ++gi) acc[gi] = 0.0f;
    float bias = ff1b[o];

    #pragma unroll 2
    for (int k = 0; k < DMODEL; k += 4) {
        float w0 = f1T[k * DFF + o];
        float w1 = f1T[(k + 1) * DFF + o];
        float w2 = f1T[(k + 2) * DFF + o];
        float w3 = f1T[(k + 3) * DFF + o];
        #pragma unroll
        for (int gi = 0; gi < 8; ++gi) {
            float4 b4 = *(const float4*)&Bs[gi][k];
            acc[gi] += b4.x * w0 + b4.y * w1 + b4.z * w2 + b4.w * w3;
        }
    }
    #pragma unroll
    for (int gi = 0; gi < 8; ++gi)
        ffb[(bg * 8 + gi) * DFF + o] = fmaxf(acc[gi] + bias, 0.0f);
}

// ---------------------------------------------------------------------------
// Head C: ff2 (split-k) + residual + LN2 + lin1 + lin2.  Block = 2 graphs.
// ---------------------------------------------------------------------------
__global__ __launch_bounds__(384) void head_ff2_kernel(
    const float* __restrict__ ffb,  const float* __restrict__ f2T,
    const float* __restrict__ ff2b, const float* __restrict__ Bln,
    const float* __restrict__ ln2g, const float* __restrict__ ln2b,
    const float* __restrict__ l1T,  const float* __restrict__ l1b,
    const float* __restrict__ l2w,  const float* __restrict__ l2b,
    float* __restrict__ out)
{
    __shared__ float ffs[2][DFF];
    __shared__ float ps[2][2][DMODEL];
    __shared__ float Cs[2][DMODEL], As2[2][DMODEL], Bs2[2][DMODEL];

    int g0 = blockIdx.x * 2, tid = threadIdx.x;

    for (int idx = tid; idx < 2 * DFF; idx += 384)
        ffs[idx >> 11][idx & (DFF - 1)] = ffb[g0 * DFF + idx];
    __syncthreads();

    int o  = (tid < DMODEL) ? tid : tid - DMODEL;
    int kh = (tid < DMODEL) ? 0 : 1;
    float acc0 = 0.0f, acc1 = 0.0f;
    int kb = kh * (DFF / 2);
    #pragma unroll 2
    for (int k = kb; k < kb + DFF / 2; k += 4) {
        float w0 = f2T[k * DMODEL + o];
        float w1 = f2T[(k + 1) * DMODEL + o];
        float w2 = f2T[(k + 2) * DMODEL + o];
        float w3 = f2T[(k + 3) * DMODEL + o];
        float4 q0 = *(const float4*)&ffs[0][k];
        float4 q1 = *(const float4*)&ffs[1][k];
        acc0 += q0.x * w0 + q0.y * w1 + q0.z * w2 + q0.w * w3;
        acc1 += q1.x * w0 + q1.y * w1 + q1.z * w2 + q1.w * w3;
    }
    ps[kh][0][o] = acc0;
    ps[kh][1][o] = acc1;
    __syncthreads();

    if (tid < DMODEL) {
        #pragma unroll
        for (int gi = 0; gi < 2; ++gi)
            Cs[gi][tid] = ff2b[tid] + ps[0][gi][tid] + ps[1][gi][tid]
                        + Bln[(g0 + gi) * DMODEL + tid];
    }
    __syncthreads();

    if (tid < DMODEL) {
        #pragma unroll
        for (int gi = 0; gi < 2; ++gi) {
            float mu = 0.0f;
            #pragma unroll
            for (int k = 0; k < DMODEL; k += 4) {
                float4 q = *(const float4*)&Cs[gi][k];
                mu += (q.x + q.y) + (q.z + q.w);
            }
            mu *= (1.0f / DMODEL);
            float var = 0.0f;
            #pragma unroll
            for (int k = 0; k < DMODEL; k += 4) {
                float4 q = *(const float4*)&Cs[gi][k];
                float d0 = q.x - mu, d1 = q.y - mu, d2 = q.z - mu, d3 = q.w - mu;
                var += (d0 * d0 + d1 * d1) + (d2 * d2 + d3 * d3);
            }
            var *= (1.0f / DMODEL);
            float rstd = rsqrtf(var + 1e-5f);
            As2[gi][tid] = (Cs[gi][tid] - mu) * rstd * ln2g[tid] + ln2b[tid];
        }
    }
    __syncthreads();

    if (tid < DMODEL) {
        #pragma unroll
        for (int gi = 0; gi < 2; ++gi) {
            float acc = l1b[tid];
            #pragma unroll 4
            for (int k = 0; k < DMODEL; k += 4) {
                float4 a4 = *(const float4*)&As2[gi][k];
                acc += a4.x * l1T[k * DMODEL + tid] + a4.y * l1T[(k + 1) * DMODEL + tid]
                     + a4.z * l1T[(k + 2) * DMODEL + tid] + a4.w * l1T[(k + 3) * DMODEL + tid];
            }
            Bs2[gi][tid] = fmaxf(acc, 0.0f);
        }
    }
    __syncthreads();

    if (tid < 2) {
        float s = 0.0f;
        #pragma unroll
        for (int k = 0; k < DMODEL; k += 4) {
            float4 b4 = *(const float4*)&Bs2[tid][k];
            float4 w4 = *(const float4*)&l2w[k];
            s += (b4.x * w4.x + b4.y * w4.y) + (b4.z * w4.z + b4.w * w4.w);
        }
        out[g0 + tid] = s + l2b[0];
    }
}

extern "C" void kernel_launch(void* const* d_in, const int* in_sizes, int n_in,
                              void* d_out, int out_size, void* d_ws, size_t ws_size,
                              hipStream_t stream)
{
    const float* x    = (const float*)d_in[0];
    const int*   ei   = (const int*)d_in[1];
    const int*   bat  = (const int*)d_in[2];
    const int    E    = in_sizes[1] / 2;
    const int*   src  = ei;
    const int*   dst  = ei + E;

    const float* nn1[8]; for (int i = 0; i < 8; ++i) nn1[i] = (const float*)d_in[3 + i];
    const float* nn2[8]; for (int i = 0; i < 8; ++i) nn2[i] = (const float*)d_in[11 + i];
    const float* qkv_w = (const float*)d_in[19];
    const float* qkv_b = (const float*)d_in[20];
    const float* aow   = (const float*)d_in[21];
    const float* aob   = (const float*)d_in[22];
    const float* ln1g  = (const float*)d_in[23];
    const float* ln1b  = (const float*)d_in[24];
    const float* ff1w  = (const float*)d_in[25];
    const float* ff1b  = (const float*)d_in[26];
    const float* ff2w  = (const float*)d_in[27];
    const float* ff2b  = (const float*)d_in[28];
    const float* ln2g  = (const float*)d_in[29];
    const float* ln2b  = (const float*)d_in[30];
    const float* l1w   = (const float*)d_in[31];
    const float* l1b   = (const float*)d_in[32];
    const float* l2w   = (const float*)d_in[33];
    const float* l2b   = (const float*)d_in[34];

    const size_t N64 = (size_t)NNODES * DHID;
    const int S1 = DMODEL * DMODEL;     // 36864
    const int S2 = DMODEL * DFF;        // 393216

    // workspace layout (fp32 activations)
    float* h1    = (float*)d_ws;                     // N64
    float* h2    = h1 + N64;
    float* pools = h2 + N64;                         // 3*G*64
    float* Bln   = pools + 3 * NGRAPH * DHID;        // G*192
    float* ffb   = Bln + NGRAPH * DMODEL;            // G*2048
    float* vwT   = ffb + NGRAPH * DFF;
    float* aowT  = vwT + S1;
    float* l1T   = aowT + S1;
    float* f1T   = l1T + S1;
    float* f2T   = f1T + S2;
    int*   cnt    = (int*)(f2T + S2);
    int*   excl   = cnt + NNODES;
    int*   rowptr = excl + NNODES;                   // N+1
    int*   cursor = rowptr + NNODES + 1;
    int*   tot    = cursor + NNODES;                 // NCH
    int*   srcs   = tot + NCH + 4;                   // E ints

    // ---- CSR build + weight transposes
    hipMemsetAsync(cnt, 0, NNODES * sizeof(int), stream);
    hipMemsetAsync(pools, 0, 3 * NGRAPH * DHID * sizeof(float), stream);
    hist_kernel<<<1024, 256, 0, stream>>>(dst, cnt, E);
    scan_chunk_kernel<<<NCH, SCAN_CHUNK, 0, stream>>>(cnt, excl, tot, NNODES);
    scan_tot_kernel<<<1, 256, 0, stream>>>(tot, NCH);
    finalize_rowptr_kernel<<<128, 256, 0, stream>>>(excl, tot, rowptr, cursor, NNODES, E);
    sort_edges_kernel<<<1024, 256, 0, stream>>>(src, dst, cursor, srcs, E);
    transpose_w_kernel<<<1024, 256, 0, stream>>>(qkv_w, aow, l1w, ff1w, ff2w,
                                                 vwT, aowT, l1T, f1T, f2T);

    const int LB = 2048;   // 8192 waves (~13 nodes each) fills 7 blocks/CU

    gin_fused_kernel<<<LB, 256, 0, stream>>>(x, rowptr, srcs,
        nn1[0], nn1[1], nn1[2], nn1[3], nn1[4], nn1[5], nn1[6], nn1[7],
        h1, pools + 0 * NGRAPH * DHID, bat);

    gin_fused_kernel<<<LB, 256, 0, stream>>>(h1, rowptr, srcs,
        nn2[0], nn2[1], nn2[2], nn2[3], nn2[4], nn2[5], nn2[6], nn2[7],
        h2, pools + 1 * NGRAPH * DHID, bat);

    gin_fused_kernel<<<LB, 256, 0, stream>>>(h2, rowptr, srcs,
        nn2[0], nn2[1], nn2[2], nn2[3], nn2[4], nn2[5], nn2[6], nn2[7],
        nullptr, pools + 2 * NGRAPH * DHID, bat);

    // ---- head
    head_a_kernel<<<NGRAPH, DMODEL, 0, stream>>>(pools, vwT, qkv_b, aowT, aob,
                                                 ln1g, ln1b, Bln);
    head_ff1_kernel<<<256, 256, 0, stream>>>(Bln, f1T, ff1b, ffb);
    head_ff2_kernel<<<NGRAPH / 2, 384, 0, stream>>>(ffb, f2T, ff2b, Bln,
        ln2g, ln2b, l1T, l1b, l2w, l2b, (float*)d_out);
}